// Round 7
// baseline (239.963 us; speedup 1.0000x reference)
//
#include <hip/hip_runtime.h>
#include <hip/hip_bf16.h>
#include <cstddef>

// 3-layer tanh RNN (B=8192, T=80, D=32, H=64), fused, MFMA.
// INTRA-WAVE SYSTOLIC: each wave runs ALL 3 layers (its j-half) as 3 independent
// dependency chains per tick. At tick tau, wave computes h0(tau), h1(tau-1),
// h2(tau-2); inputs h0(tau-1), h1(tau-2), h2(tau-3) were ALL written at tick
// tau-1 -> 3 full-k LDS reads/tick, each shared by two segments. 1 barrier/tick.
//
// Block = 256 thr = 4 waves = 2 batch-groups x 2 j-halves; grid = 256 (B/32)
// -> 1 block/CU, one wave per SIMD everywhere, 3-way ILP inside each wave.
//
// MFMA 16x16x32 bf16, A = weights (VGPR-resident, ~22 frags), B = activations:
//   A-frag: lane holds A[m=lane&15][k=8*(lane>>4)+i]
//   B-frag: lane holds B[k=8*(lane>>4)+i][n=lane&15]
//   C/D:    lane holds D[row=4*(lane>>4)+r][col=lane&15]   (verified R2-R6)
// h exchange: hb[group][layer][parity][batch][j] (stride 72 shorts), parity =
// write-tick & 1. Both parities zero-initialized once => first-tick recurrent
// reads are the correct zero initial state. Per-layer validity guards are
// wave-uniform (L0: tau<=79, L1: 1<=tau<=80, L2: tau>=2).
// __syncthreads (NOT raw barrier: R6 regressed 88->130 us).

typedef __attribute__((ext_vector_type(8))) short s16x8;
typedef __attribute__((ext_vector_type(4))) short s16x4;
typedef __attribute__((ext_vector_type(4))) float fx4;

#define MFMA16(A, B, C) __builtin_amdgcn_mfma_f32_16x16x32_bf16((A), (B), (C), 0, 0, 0)

#if __has_builtin(__builtin_amdgcn_exp2f)
#define EXP2F(x) __builtin_amdgcn_exp2f(x)
#else
#define EXP2F(x) exp2f(x)
#endif
#if __has_builtin(__builtin_amdgcn_rcpf)
#define RCPF(x) __builtin_amdgcn_rcpf(x)
#else
#define RCPF(x) (1.0f / (x))
#endif

static constexpr float K2LOG2E = 2.8853900817779268f;  // 2*log2(e)

__device__ __forceinline__ short f2bf(float f) {  // RNE float->bf16 (weights, one-time)
  union { float f; unsigned u; } v; v.f = f;
  unsigned r = v.u + 0x7FFFu + ((v.u >> 16) & 1u);
  return (short)(r >> 16);
}
__device__ __forceinline__ unsigned pk2bf(float a, float b) {  // v_cvt_pk_bf16_f32
  float2 t; t.x = a; t.y = b;
  union { __hip_bfloat162 h; unsigned u; } c;
  c.h = __float22bfloat162_rn(t);
  return c.u;
}

__device__ __forceinline__ s16x8 wfragA(const float* W, int ncols, int row, int col0) {
  const float* p = W + row * ncols + col0;
  s16x8 r;
#pragma unroll
  for (int i = 0; i < 8; ++i) r[i] = f2bf(p[i]);
  return r;
}

// tanh(acc+bias), bias pre-scaled by 2*log2(e); returns h, writes packed bf16 x4.
__device__ __forceinline__ void tanh_pack_store(const fx4 acc, const float* bs,
                                                short* wp, float* hout) {
  float h[4];
#pragma unroll
  for (int r = 0; r < 4; ++r) {
    float e = EXP2F(__builtin_fmaf(acc[r], K2LOG2E, bs[r]));
    h[r] = __builtin_fmaf(-2.f, RCPF(e + 1.f), 1.f);
    if (hout) hout[r] = h[r];
  }
  union { unsigned u[2]; s16x4 v; } pk;
  pk.u[0] = pk2bf(h[0], h[1]);
  pk.u[1] = pk2bf(h[2], h[3]);
  *(s16x4*)wp = pk.v;
}

__global__ __launch_bounds__(256, 1) void rnn3_sys(
    const float* __restrict__ x,
    const float* __restrict__ Wih0, const float* __restrict__ Whh0,
    const float* __restrict__ bih0, const float* __restrict__ bhh0,
    const float* __restrict__ Wih1, const float* __restrict__ Whh1,
    const float* __restrict__ bih1, const float* __restrict__ bhh1,
    const float* __restrict__ Wih2, const float* __restrict__ Whh2,
    const float* __restrict__ bih2, const float* __restrict__ bhh2,
    const float* __restrict__ Wfc, const float* __restrict__ bfc,
    float* __restrict__ out)
{
  __shared__ __align__(16) short hb[2][3][2][16][72];  // [grp][layer][par][b][j], 27648 B

  const int tid = threadIdx.x;
  const int wvu = __builtin_amdgcn_readfirstlane(tid >> 6);  // 0..3
  const int g   = wvu >> 1;       // batch group
  const int s   = wvu & 1;        // j-half
  const int ln  = tid & 63;
  const int q   = ln >> 4;
  const int m15 = ln & 15;
  const int bbase = (int)blockIdx.x * 32 + g * 16;

  // ---------- zero-init ALL hb (both parities == zero initial h state) ----------
  {
    const s16x8 z = {0, 0, 0, 0, 0, 0, 0, 0};
    s16x8* pz = (s16x8*)&hb[0][0][0][0][0];
    for (int i = tid; i < (int)(sizeof(hb) / 16); i += 256) pz[i] = z;
  }

  // ---------- weights: this wave's j-half of ALL 3 layers (VGPR-resident) -------
  // rows j = 32s + 16*tile + m15; k-frag kf covers k in [32kf, 32kf+32)
  s16x8 wi0[2], wh0[2][2], wi1[2][2], wh1[2][2], wi2[2][2], wh2[2][2];
#pragma unroll
  for (int tile = 0; tile < 2; ++tile) {
    const int row = 32 * s + 16 * tile + m15;
    wi0[tile] = wfragA(Wih0, 32, row, 8 * q);
#pragma unroll
    for (int kf = 0; kf < 2; ++kf) {
      const int c = 32 * kf + 8 * q;
      wh0[tile][kf] = wfragA(Whh0, 64, row, c);
      wi1[tile][kf] = wfragA(Wih1, 64, row, c);
      wh1[tile][kf] = wfragA(Whh1, 64, row, c);
      wi2[tile][kf] = wfragA(Wih2, 64, row, c);
      wh2[tile][kf] = wfragA(Whh2, 64, row, c);
    }
  }

  // ---------- biases pre-scaled; lane's j = 32s + 16*tile + 4q + r ----------
  float bs[3][2][4];
#pragma unroll
  for (int tile = 0; tile < 2; ++tile)
#pragma unroll
    for (int r = 0; r < 4; ++r) {
      const int j = 32 * s + 16 * tile + 4 * q + r;
      bs[0][tile][r] = (bih0[j] + bhh0[j]) * K2LOG2E;
      bs[1][tile][r] = (bih1[j] + bhh1[j]) * K2LOG2E;
      bs[2][tile][r] = (bih2[j] + bhh2[j]) * K2LOG2E;
    }

  // ---------- LDS lane pointers ----------
  short* wrp[3][2];        // write base, col 32s + 4q
  const short* rdp[3][2];  // read base, col 8q
#pragma unroll
  for (int l = 0; l < 3; ++l)
#pragma unroll
    for (int p = 0; p < 2; ++p) {
      wrp[l][p] = &hb[g][l][p][m15][32 * s + 4 * q];
      rdp[l][p] = &hb[g][l][p][m15][8 * q];
    }

  // x source: lane reads x[bbase+m15][t][8q..8q+7]; both j-half waves load same x.
  const float* xr = x + (size_t)(bbase + m15) * (80 * 32) + 8 * q;
  fx4 xa = *(const fx4*)(xr);
  fx4 xb = *(const fx4*)(xr + 4);

  const fx4 z4 = {0.f, 0.f, 0.f, 0.f};
  float hk2[2][4];   // L2 tanh outputs; after the loop == h2(79)

  __syncthreads();   // zero-init visible

  for (int tau = 0; tau < 82; ++tau) {
    const int p  = tau & 1;
    const int pm = p ^ 1;          // parity of tick tau-1

    // ---- tick-top LDS reads (all written at tick tau-1, or zero-init) ----
    s16x8 h0a = *(const s16x8*)(rdp[0][pm]);
    s16x8 h0b = *(const s16x8*)(rdp[0][pm] + 32);
    s16x8 h1a = *(const s16x8*)(rdp[1][pm]);
    s16x8 h1b = *(const s16x8*)(rdp[1][pm] + 32);
    s16x8 h2a = *(const s16x8*)(rdp[2][pm]);
    s16x8 h2b = *(const s16x8*)(rdp[2][pm] + 32);

    // ---- L0: h0(tau) = tanh(Wih0 x(tau) + Whh0 h0(tau-1)) ----
    if (tau <= 79) {
      union { unsigned u[4]; s16x8 v; } xp;
      xp.u[0] = pk2bf(xa[0], xa[1]); xp.u[1] = pk2bf(xa[2], xa[3]);
      xp.u[2] = pk2bf(xb[0], xb[1]); xp.u[3] = pk2bf(xb[2], xb[3]);
      const int tn = (tau < 79) ? tau + 1 : 79;     // prefetch x(tau+1)
      xa = *(const fx4*)(xr + tn * 32);
      xb = *(const fx4*)(xr + tn * 32 + 4);
#pragma unroll
      for (int tile = 0; tile < 2; ++tile) {
        fx4 a = MFMA16(wi0[tile], xp.v, z4);
        a = MFMA16(wh0[tile][0], h0a, a);
        a = MFMA16(wh0[tile][1], h0b, a);
        tanh_pack_store(a, bs[0][tile], wrp[0][p] + 16 * tile, nullptr);
      }
    }
    // ---- L1: h1(tau-1) = tanh(Wih1 h0(tau-1) + Whh1 h1(tau-2)) ----
    if (1 <= tau && tau <= 80) {
#pragma unroll
      for (int tile = 0; tile < 2; ++tile) {
        fx4 a = MFMA16(wi1[tile][0], h0a, z4);
        a = MFMA16(wi1[tile][1], h0b, a);
        a = MFMA16(wh1[tile][0], h1a, a);
        a = MFMA16(wh1[tile][1], h1b, a);
        tanh_pack_store(a, bs[1][tile], wrp[1][p] + 16 * tile, nullptr);
      }
    }
    // ---- L2: h2(tau-2) = tanh(Wih2 h1(tau-2) + Whh2 h2(tau-3)) ----
    if (tau >= 2) {
#pragma unroll
      for (int tile = 0; tile < 2; ++tile) {
        fx4 a = MFMA16(wi2[tile][0], h1a, z4);
        a = MFMA16(wi2[tile][1], h1b, a);
        a = MFMA16(wh2[tile][0], h2a, a);
        a = MFMA16(wh2[tile][1], h2b, a);
        tanh_pack_store(a, bs[2][tile], wrp[2][p] + 16 * tile, hk2[tile]);
      }
    }
    __syncthreads();               // ONE barrier per tick
  }

  // ---------- FC head: hk2 == h2(79) (computed at tau=81) ----------
  float sv = 0.f;
#pragma unroll
  for (int tile = 0; tile < 2; ++tile)
#pragma unroll
    for (int r = 0; r < 4; ++r)
      sv += hk2[tile][r] * Wfc[32 * s + 16 * tile + 4 * q + r];
  sv += __shfl_xor(sv, 16, 64);
  sv += __shfl_xor(sv, 32, 64);
  // cross-j-half combine via LDS (reuse hb; last barrier already passed)
  float* fcb = (float*)&hb[0][0][0][0][0];   // [g*2+s][16]
  if (ln < 16) fcb[(g * 2 + s) * 16 + ln] = sv;
  __syncthreads();
  if (s == 0 && ln < 16)
    out[bbase + ln] = fcb[(g * 2 + 0) * 16 + ln] + fcb[(g * 2 + 1) * 16 + ln] + bfc[0];
}

extern "C" void kernel_launch(void* const* d_in, const int* in_sizes, int n_in,
                              void* d_out, int out_size, void* d_ws, size_t ws_size,
                              hipStream_t stream) {
  const float* x    = (const float*)d_in[0];
  const float* Wih0 = (const float*)d_in[1];
  const float* Whh0 = (const float*)d_in[2];
  const float* bih0 = (const float*)d_in[3];
  const float* bhh0 = (const float*)d_in[4];
  const float* Wih1 = (const float*)d_in[5];
  const float* Whh1 = (const float*)d_in[6];
  const float* bih1 = (const float*)d_in[7];
  const float* bhh1 = (const float*)d_in[8];
  const float* Wih2 = (const float*)d_in[9];
  const float* Whh2 = (const float*)d_in[10];
  const float* bih2 = (const float*)d_in[11];
  const float* bhh2 = (const float*)d_in[12];
  const float* Wfc  = (const float*)d_in[13];
  const float* bfc  = (const float*)d_in[14];

  // 256 blocks x 256 thr = 4 waves/block (2 batch-groups x 2 j-halves),
  // 1 block/CU -> one wave per SIMD, 3 independent layer-chains per wave.
  rnn3_sys<<<dim3(256), dim3(256), 0, stream>>>(
      x, Wih0, Whh0, bih0, bhh0, Wih1, Whh1, bih1, bhh1,
      Wih2, Whh2, bih2, bhh2, Wfc, bfc, (float*)d_out);
}

// Round 8
// 195.781 us; speedup vs baseline: 1.2257x; 1.2257x over previous
//
#include <hip/hip_runtime.h>
#include <hip/hip_bf16.h>
#include <cstddef>

// 3-layer tanh RNN (B=8192, T=80, D=32, H=64), fused, MFMA, systolic layer pipeline
// (R4 structure) + CHUNKED x REGISTER PIPELINE.
//
// Block = 192 thr = 3 waves; wave wv computes LAYER wv at local time lt = tau - wv.
// One __syncthreads per tick. R3-R7 invariant (~90us regardless of barriers/waves/ILP)
// is explained by per-tick HBM exposure of the uncoalesced x load: every tick's
// barrier emits s_waitcnt vmcnt(0), draining that tick's x prefetch (~900+ cyc,
// unhidden -- all waves barrier-locked in phase). Fix: wave 0 preloads x in 8-tick
// chunks (16x global_load_dwordx4 into 64 VGPRs, issued in tick i==7 after slot-7's
// use) -> one pipelined drain per 8 ticks instead of 8 serial drains.
//
// MFMA 16x16x32 bf16, A = weights (VGPR-resident), B = activations:
//   A-frag: lane holds A[m=lane&15][k=8*(lane>>4)+i]
//   B-frag: lane holds B[k=8*(lane>>4)+i][n=lane&15]
//   C/D:    lane holds D[row=4*(lane>>4)+r][col=lane&15]      (verified R2-R7)
// h exchange: hb[layer][t&1][batch][j] (stride 72 shorts). Own-recurrence
// transpose read back pre-barrier (same-wave DS order => RAW safe).
// Plain __syncthreads (R6's clobbered raw barrier regressed: codegen wreckage).

typedef __attribute__((ext_vector_type(8))) short s16x8;
typedef __attribute__((ext_vector_type(4))) short s16x4;
typedef __attribute__((ext_vector_type(4))) float fx4;

#define MFMA16(A, B, C) __builtin_amdgcn_mfma_f32_16x16x32_bf16((A), (B), (C), 0, 0, 0)

#if __has_builtin(__builtin_amdgcn_exp2f)
#define EXP2F(x) __builtin_amdgcn_exp2f(x)
#else
#define EXP2F(x) exp2f(x)
#endif
#if __has_builtin(__builtin_amdgcn_rcpf)
#define RCPF(x) __builtin_amdgcn_rcpf(x)
#else
#define RCPF(x) (1.0f / (x))
#endif

static constexpr float K2LOG2E = 2.8853900817779268f;  // 2*log2(e)

__device__ __forceinline__ short f2bf(float f) {  // RNE float->bf16 (weights, one-time)
  union { float f; unsigned u; } v; v.f = f;
  unsigned r = v.u + 0x7FFFu + ((v.u >> 16) & 1u);
  return (short)(r >> 16);
}
__device__ __forceinline__ unsigned pk2bf(float a, float b) {  // v_cvt_pk_bf16_f32
  float2 t; t.x = a; t.y = b;
  union { __hip_bfloat162 h; unsigned u; } c;
  c.h = __float22bfloat162_rn(t);
  return c.u;
}

__device__ __forceinline__ s16x8 wfragA(const float* W, int ncols, int row, int col0) {
  const float* p = W + row * ncols + col0;
  s16x8 r;
#pragma unroll
  for (int i = 0; i < 8; ++i) r[i] = f2bf(p[i]);
  return r;
}

__global__ __launch_bounds__(192, 2) void rnn3_pipe_xc(
    const float* __restrict__ x,
    const float* __restrict__ Wih0, const float* __restrict__ Whh0,
    const float* __restrict__ bih0, const float* __restrict__ bhh0,
    const float* __restrict__ Wih1, const float* __restrict__ Whh1,
    const float* __restrict__ bih1, const float* __restrict__ bhh1,
    const float* __restrict__ Wih2, const float* __restrict__ Whh2,
    const float* __restrict__ bih2, const float* __restrict__ bhh2,
    const float* __restrict__ Wfc, const float* __restrict__ bfc,
    float* __restrict__ out)
{
  __shared__ __align__(16) short hb[3][2][16][72];  // [layer][t&1][batch][j], 13824 B

  const int tid = threadIdx.x;
  const int wv  = __builtin_amdgcn_readfirstlane(tid >> 6);  // 0..2 == layer
  const int ln  = tid & 63;
  const int q   = ln >> 4;
  const int m15 = ln & 15;
  const int bbase = (int)blockIdx.x * 16;

  // ---------- this wave's layer parameters ----------
  const float* Wih = (wv == 0) ? Wih0 : (wv == 1) ? Wih1 : Wih2;
  const float* Whh = (wv == 0) ? Whh0 : (wv == 1) ? Whh1 : Whh2;
  const float* bi  = (wv == 0) ? bih0 : (wv == 1) ? bih1 : bih2;
  const float* bh  = (wv == 0) ? bhh0 : (wv == 1) ? bhh1 : bhh2;
  const int kin = (wv == 0) ? 32 : 64;   // input width (x vs h)

  // ---------- weight A-fragments, all 4 j-tiles of this layer (VGPR-resident) ----
  s16x8 wi0[4], wi1[4], wh0[4], wh1[4];
  const s16x8 z8 = {0, 0, 0, 0, 0, 0, 0, 0};
#pragma unroll
  for (int tile = 0; tile < 4; ++tile) {
    const int row = 16 * tile + m15;
    wi0[tile] = wfragA(Wih, kin, row, 8 * q);
    wi1[tile] = wv ? wfragA(Wih, 64, row, 32 + 8 * q) : z8;   // layer 0: K=32 only
    wh0[tile] = wfragA(Whh, 64, row, 8 * q);
    wh1[tile] = wfragA(Whh, 64, row, 32 + 8 * q);
  }

  // ---------- biases pre-scaled by 2*log2(e); lane's j = 16*tile + 4*q + r ------
  float bsc[4][4];
#pragma unroll
  for (int tile = 0; tile < 4; ++tile)
#pragma unroll
    for (int r = 0; r < 4; ++r) {
      const int j = 16 * tile + 4 * q + r;
      bsc[tile][r] = (bi[j] + bh[j]) * K2LOG2E;
    }

  const fx4 z4 = {0.f, 0.f, 0.f, 0.f};
  s16x8 r0 = z8, r1 = z8;          // own recurrent state h_wv(t-1), B-layout

  // ---------- wave-0 x chunk buffer: slot i holds x(lt) for lt = 8*chunk + i ----
  const float* xr = x + (size_t)(bbase + m15) * (80 * 32) + 8 * q;
  fx4 xb0[8], xb1[8];
  if (wv == 0) {
#pragma unroll
    for (int j = 0; j < 8; ++j) {          // preload chunk 0: t = 0..7
      xb0[j] = *(const fx4*)(xr + j * 32);
      xb1[j] = *(const fx4*)(xr + j * 32 + 4);
    }
  }

  float hk[4][4];                  // tanh outputs of the last computed tick (FC use)

  for (int chunk = 0; chunk < 11; ++chunk) {
#pragma unroll
    for (int i = 0; i < 8; ++i) {
      const int tau = chunk * 8 + i;
      const int lt = tau - wv;                 // this wave's time step
      if (0 <= lt && lt < 80) {                // wave-uniform guard
        const int p = lt & 1;
        // ---- input B-frags ----
        s16x8 in0, in1;
        if (wv) {
          const short* up = &hb[wv - 1][p][m15][8 * q];   // h_{wv-1}(lt), upstream
          in0 = *(const s16x8*)(up);
          in1 = *(const s16x8*)(up + 32);
        } else {
          const fx4 xc0 = xb0[i], xc1 = xb1[i];           // loaded a chunk ago
          union { unsigned u[4]; s16x8 v; } xp;
          xp.u[0] = pk2bf(xc0[0], xc0[1]); xp.u[1] = pk2bf(xc0[2], xc0[3]);
          xp.u[2] = pk2bf(xc1[0], xc1[1]); xp.u[3] = pk2bf(xc1[2], xc1[3]);
          in0 = xp.v; in1 = z8;
        }
        // ---- MFMA: Whh*rec first (registers ready) to hide the upstream ds_read --
        fx4 acc[4];
#pragma unroll
        for (int tile = 0; tile < 4; ++tile) acc[tile] = MFMA16(wh0[tile], r0, z4);
#pragma unroll
        for (int tile = 0; tile < 4; ++tile) acc[tile] = MFMA16(wh1[tile], r1, acc[tile]);
#pragma unroll
        for (int tile = 0; tile < 4; ++tile) acc[tile] = MFMA16(wi0[tile], in0, acc[tile]);
        if (wv) {
#pragma unroll
          for (int tile = 0; tile < 4; ++tile) acc[tile] = MFMA16(wi1[tile], in1, acc[tile]);
        }
        // ---- tanh + pack + store h_wv(lt) ----
        short* wb = &hb[wv][p][m15][4 * q];
#pragma unroll
        for (int tile = 0; tile < 4; ++tile) {
          float h[4];
#pragma unroll
          for (int r = 0; r < 4; ++r) {
            float e = EXP2F(__builtin_fmaf(acc[tile][r], K2LOG2E, bsc[tile][r]));
            h[r] = __builtin_fmaf(-2.f, RCPF(e + 1.f), 1.f);
            hk[tile][r] = h[r];
          }
          union { unsigned u[2]; s16x4 v; } pk;
          pk.u[0] = pk2bf(h[0], h[1]);
          pk.u[1] = pk2bf(h[2], h[3]);
          *(s16x4*)(wb + 16 * tile) = pk.v;
        }
        // ---- own-recurrence transpose readback (pre-barrier; same-wave RAW safe) --
        const short* ow = &hb[wv][p][m15][8 * q];
        r0 = *(const s16x8*)(ow);
        r1 = *(const s16x8*)(ow + 32);
      }
      // ---- chunk refill: 16 loads issued together, drained by ONE barrier ----
      if (i == 7 && wv == 0) {
        const int tb = tau + 1;                // next chunk's first t (wave0: lt=tau)
        if (tb <= 79) {
#pragma unroll
          for (int j = 0; j < 8; ++j) {
            const int tt = (tb + j <= 79) ? tb + j : 79;
            xb0[j] = *(const fx4*)(xr + tt * 32);
            xb1[j] = *(const fx4*)(xr + tt * 32 + 4);
          }
        }
      }
      __syncthreads();                         // ONE barrier per tick
    }
  }

  // ---------- FC head: wave 2's last tick (tau=81) produced h2(79) in hk ----------
  if (wv == 2) {
    float s = 0.f;
#pragma unroll
    for (int tile = 0; tile < 4; ++tile)
#pragma unroll
      for (int r = 0; r < 4; ++r)
        s += hk[tile][r] * Wfc[16 * tile + 4 * q + r];
    s += __shfl_xor(s, 16, 64);
    s += __shfl_xor(s, 32, 64);
    if (ln < 16) out[bbase + ln] = s + bfc[0];
  }
}

extern "C" void kernel_launch(void* const* d_in, const int* in_sizes, int n_in,
                              void* d_out, int out_size, void* d_ws, size_t ws_size,
                              hipStream_t stream) {
  const float* x    = (const float*)d_in[0];
  const float* Wih0 = (const float*)d_in[1];
  const float* Whh0 = (const float*)d_in[2];
  const float* bih0 = (const float*)d_in[3];
  const float* bhh0 = (const float*)d_in[4];
  const float* Wih1 = (const float*)d_in[5];
  const float* Whh1 = (const float*)d_in[6];
  const float* bih1 = (const float*)d_in[7];
  const float* bhh1 = (const float*)d_in[8];
  const float* Wih2 = (const float*)d_in[9];
  const float* Whh2 = (const float*)d_in[10];
  const float* bih2 = (const float*)d_in[11];
  const float* bhh2 = (const float*)d_in[12];
  const float* Wfc  = (const float*)d_in[13];
  const float* bfc  = (const float*)d_in[14];

  // 512 blocks x 192 thr (3 waves = 3 pipelined layers), 16 batch rows per block.
  rnn3_pipe_xc<<<dim3(512), dim3(192), 0, stream>>>(
      x, Wih0, Whh0, bih0, bhh0, Wih1, Whh1, bih1, bhh1,
      Wih2, Whh2, bih2, bhh2, Wfc, bfc, (float*)d_out);
}